// Round 3
// baseline (1287.460 us; speedup 1.0000x reference)
//
#include <hip/hip_runtime.h>
#include <math.h>

#define KK 128
#define EE 4096
#define MM 512
#define CP 32   // max nnz per q_kn row (c<=32 verified: absmax exactly 0 in prior rounds)
#define NB 1024 // mega-kernel grid: 4 blocks/CU x 256 CUs, co-resident by __launch_bounds__(256,4)

// ws float-offset layout (~72 MB of the 1 GiB ws):
#define OFF_U    0              // u[128] (current state)
#define OFF_PA   128            // partials A [128][8]
#define OFF_PB   2176           // partials B [128][8]
#define OFF_BAR  3200           // grid-barrier words (1024 u32, zeroed by k_setup)
#define OFF_CNT  4224           // int cnt[E]
#define OFF_IDX  8320           // signed char idx[E][CP]  (row-major, sentinel -1)
#define OFF_IDXT 41088          // signed char idxT[CP][E] (i-major, sentinel -1)
#define OFF_PE   73856          // P01, a2, scv, invd, bz  (5 x E floats)
#define OFF_GW   94336          // gW[k][e] = ukc*W*beiTa_1
#define OFF_HW   618624         // hW[k][e] = ukc*W
#define OFF_BC   1142912        // Bc[k][i][e] compacted B (64 MB)

// K1: blocks 0..15 per-e lists + constants + u0 + barrier zero; blocks 16..271 gW/hW.
__global__ __launch_bounds__(256) void k_setup(
    const float* __restrict__ U, const float* __restrict__ W,
    const float* __restrict__ beiTa_1, const float* __restrict__ beiTa_2,
    const float* __restrict__ guess_slip, const float* __restrict__ A_emb,
    const float* __restrict__ gamma_c, const float* __restrict__ score,
    const float* __restrict__ ukc, const float* __restrict__ q_kn,
    const float* __restrict__ d, const int* __restrict__ stu_id,
    float* __restrict__ ws)
{
    int tid = threadIdx.x;
    int blk = blockIdx.x;
    if (blk < 16) {
        int e = blk * 256 + tid;
        int* cnt = (int*)(ws + OFF_CNT);
        signed char* idx  = (signed char*)(ws + OFF_IDX);
        signed char* idxT = (signed char*)(ws + OFF_IDXT);
        float* P01  = ws + OFF_PE;
        float* a2   = P01 + EE;
        float* scv  = a2 + EE;
        float* invd = scv + EE;
        float* bz   = invd + EE;

        // sentinel-fill this e's idx row (-1 bytes), then pack ascending support
        int* ip32 = (int*)(idx + e * CP);
        #pragma unroll
        for (int t = 0; t < CP / 4; t++) ip32[t] = -1;
        const float4* qrow = (const float4*)(q_kn + (size_t)e * KK);
        int c = 0;
        for (int j4 = 0; j4 < KK / 4; j4++) {
            float4 q = qrow[j4];
            int j = j4 * 4;
            if (q.x > 0.5f) { if (c < CP) idx[e*CP+c] = (signed char)j;     c++; }
            if (q.y > 0.5f) { if (c < CP) idx[e*CP+c] = (signed char)(j+1); c++; }
            if (q.z > 0.5f) { if (c < CP) idx[e*CP+c] = (signed char)(j+2); c++; }
            if (q.w > 0.5f) { if (c < CP) idx[e*CP+c] = (signed char)(j+3); c++; }
        }
        c = (c < CP) ? c : CP;
        cnt[e] = c;
        // transposed copy (coalesced over e for each i)
        for (int i = 0; i < CP; i++) idxT[(size_t)i * EE + e] = idx[e * CP + i];

        float id_ = 1.0f / d[e];
        invd[e] = id_;
        float scr = score[e];
        scv[e] = scr;
        P01[e] = A_emb[3*e] * (1.0f - guess_slip[2*e]) +
                 A_emb[3*e+1] * (1.0f - guess_slip[2*e+1]);
        a2[e] = A_emb[3*e+2];
        float zc = 1.0f / (1.0f + __expf(gamma_c[e] * id_ * (scr - 0.5f))) - 0.5f;
        bz[e] = beiTa_2[e] * zc;

        if (blk == 0) {
            if (tid < KK) ws[tid] = U[(size_t)stu_id[0] * KK + tid];
            // zero grid-barrier words (ws is poisoned between runs)
            unsigned* bar = (unsigned*)(ws + OFF_BAR);
            for (int t = tid; t < 1024; t += 256) bar[t] = 0u;
        }
    } else {
        float* gW = ws + OFF_GW;
        float* hW = ws + OFF_HW;
        int stride = 256 * 256;
        for (int t = (blk - 16) * 256 + tid; t < KK * EE; t += stride) {
            float uw = ukc[t] * W[t];
            hW[t] = uw;
            gW[t] = uw * beiTa_1[t];
        }
    }
}

// Two-level grid barrier, v2 (the r2 version starved workers via ~1000 spinners
// hammering ONE line at s_sleep(1); this one spins on 32 per-group release lines
// at s_sleep(16) ~ 0.43us poll -> spin traffic down ~4 orders of magnitude).
// Counters ACCUMULATE across calls (no reset race); call n passes gen=n, group
// counter reaches 32n, master counter reaches 32n, releaser stores gen into the
// 32 per-group release words. All NB blocks co-resident (grid == capacity).
// Word layout in bar[1024]: gctr[g] at g*8; mctr at 256; ggen[g] at 272+g*8.
__device__ __forceinline__ void gridbar(unsigned* bar, int bid, unsigned gen)
{
    __syncthreads();
    if (threadIdx.x == 0) {
        __threadfence();                              // release my block's writes
        unsigned* gctr = bar + (bid >> 5) * 8;
        unsigned* mctr = bar + 256;
        unsigned* ggen = bar + 272;
        unsigned* mygen = ggen + (bid >> 5) * 8;
        unsigned target = 32u * gen;
        bool released = false;
        if (__hip_atomic_fetch_add(gctr, 1u, __ATOMIC_ACQ_REL, __HIP_MEMORY_SCOPE_AGENT) == target - 1u) {
            if (__hip_atomic_fetch_add(mctr, 1u, __ATOMIC_ACQ_REL, __HIP_MEMORY_SCOPE_AGENT) == target - 1u) {
                #pragma unroll
                for (int g = 0; g < 32; g++)
                    __hip_atomic_store(ggen + g * 8, gen, __ATOMIC_RELEASE, __HIP_MEMORY_SCOPE_AGENT);
                released = true;
            }
        }
        if (!released) {
            while (__hip_atomic_load(mygen, __ATOMIC_ACQUIRE, __HIP_MEMORY_SCOPE_AGENT) < gen)
                __builtin_amdgcn_s_sleep(16);
        }
        __threadfence();
    }
    __syncthreads();
}

// K2 (mega): B-compaction + 3 model phases + final, one dispatch.
// KEY CHANGE vs r2: block (k=bid&127, ec=bid>>7) compacts EXACTLY the 8 units
// (k, e0=ec*512+t*64) whose Bc slice it alone reads in the phases -> no grid
// barrier between compaction and phase 0, and Bc traffic is same-block/same-XCD.
__global__ __launch_bounds__(256, 4) void k_mega(
    const float* __restrict__ B, float* __restrict__ ws, float* __restrict__ out,
    const int* __restrict__ ex_id, const float* __restrict__ alpha,
    const float* __restrict__ gamma_e)
{
    __shared__ float lds[64 * KK];   // 32 KB
    int tid = threadIdx.x;
    int bid = blockIdx.x;
    unsigned* bar = (unsigned*)(ws + OFF_BAR);

    const int* cnt = (const int*)(ws + OFF_CNT);
    const signed char* idxT = (const signed char*)(ws + OFF_IDXT);
    const float* P01  = ws + OFF_PE;
    const float* a2   = P01 + EE;
    const float* scv  = a2 + EE;
    const float* invd = scv + EE;
    const float* bzv  = invd + EE;
    const float* gW   = ws + OFF_GW;
    const float* hW   = ws + OFF_HW;
    float* Bc = ws + OFF_BC;
    float* pA = ws + OFF_PA;
    float* pB = ws + OFF_PB;

    int k  = bid & 127;
    int ec = bid >> 7;         // 0..7

    // ---- Stage 1: compact my own 8 units (k, e0 in [ec*512, ec*512+512)) ----
    for (int t8 = 0; t8 < 8; t8++) {
        int e0 = ec * 512 + t8 * 64;
        const float4* src = (const float4*)(B + ((size_t)k * EE + e0) * KK);
        float4* dst4 = (float4*)lds;
        #pragma unroll
        for (int it = 0; it < 8; it++)
            dst4[it * 256 + tid] = src[it * 256 + tid];
        __syncthreads();
        int eo = tid & 63;
        float* BcB = Bc + (size_t)k * CP * EE + e0 + eo;
        for (int i = tid >> 6; i < CP; i += 4) {
            int j = idxT[(size_t)i * EE + e0 + eo];
            unsigned long long m = __ballot(j >= 0);
            if (!m) break;
            if (j >= 0) BcB[(size_t)i * EE] = lds[eo * KK + j];
        }
        __syncthreads();
    }
    // no grid barrier needed: every Bc value read below was written above by THIS block

    // ---- Stage 2: three phases ----
    float* lu   = lds;         // [128]
    float* sdv  = lds + 128;   // [128]
    float* red2 = lds + 256;   // [128]
    float* wred = lds + 384;   // [4]

    for (int p = 0; p < 3; p++) {
        const float* pin = (p == 2) ? pB : pA;
        float* pout      = (p == 1) ? pB : pA;

        if (tid < KK) {
            float uv;
            if (p == 0) {
                uv = ws[tid];
            } else {
                float s = 0.0f;
                const float* pp = pin + tid * 8;
                #pragma unroll
                for (int t = 0; t < 8; t++) s += pp[t];
                uv = 1.0f / (1.0f + __expf(s));
            }
            lu[tid] = uv;
            float t = uv - 0.5f;
            sdv[tid] = (fabsf(t) > 0.05f) ? t : 0.0f;
        }
        __syncthreads();

        float vacc = 0.0f;
        #pragma unroll
        for (int sub = 0; sub < 2; sub++) {
            int e = ec * 512 + sub * 256 + tid;
            int c = cnt[e];
            const signed char* it = idxT + e;
            const float* bp = Bc + (size_t)k * CP * EE + e;
            float su = 0.0f, gs = 0.0f;
            for (int i = 0; i < c; i++) {
                int j   = it[(size_t)i * EE];
                float b = bp[(size_t)i * EE];
                su += lu[j];
                gs = fmaf(b, (j != k) ? sdv[j] : 0.0f, gs);   // diag term cancels exactly
            }
            float t0 = scv[e] - su * invd[e];
            float yc = __expf(-t0 * t0);
            float Ic = 1.0f / (1.0f + __expf(P01[e] + a2[e] * yc));
            float Gkc = 1.0f / (1.0f + __expf(gs)) - 1.0f;
            size_t o = (size_t)k * EE + e;
            vacc += Ic * (gW[o] * Gkc + hW[o] * bzv[e]);
        }
        #pragma unroll
        for (int m = 1; m < 64; m <<= 1) vacc += __shfl_xor(vacc, m);
        if ((tid & 63) == 0) wred[tid >> 6] = vacc;
        __syncthreads();
        if (tid == 0) pout[k * 8 + ec] = wred[0] + wred[1] + wred[2] + wred[3];

        // bookkeeping on block 0: diff norm, advance ws-u, state_2nd_last
        if (bid == 0 && p >= 1) {
            if (tid < KK) {
                float dd = lu[tid] - ws[tid];
                red2[tid] = dd * dd;
            }
            __syncthreads();
            for (int s2 = 64; s2 > 0; s2 >>= 1) {
                if (tid < s2) red2[tid] += red2[tid + s2];
                __syncthreads();
            }
            if (tid == 0) out[768 + (p - 1)] = sqrtf(red2[0]);
            if (tid < KK) {
                ws[tid] = lu[tid];
                if (p == 2) out[128 + tid] = lu[tid];   // state_2nd_last
            }
        }
        gridbar(bar, bid, (unsigned)(p + 1));
    }

    // ---- Stage 3: final (blocks 0,1 only; no barrier after) ----
    if (bid >= 2) return;
    if (tid < KK) {
        float s = 0.0f;
        const float* pp = pA + tid * 8;   // phase 2 wrote pA
        #pragma unroll
        for (int t = 0; t < 8; t++) s += pp[t];
        float un = 1.0f / (1.0f + __expf(s));
        lu[tid] = un;
        if (bid == 0) {
            float dd = un - ws[tid];
            red2[tid] = dd * dd;
            out[tid] = un;   // state_last
        }
    }
    __syncthreads();
    if (bid == 0) {
        for (int s2 = 64; s2 > 0; s2 >>= 1) {
            if (tid < s2) red2[tid] += red2[tid + s2];
            __syncthreads();
        }
        if (tid == 0) out[770] = sqrtf(red2[0]);
    }
    const signed char* idx = (const signed char*)(ws + OFF_IDX);
    int m = bid * 256 + tid;              // 0..511
    int e = ex_id[m];
    int c = cnt[e];
    const signed char* ip = idx + (size_t)e * CP;
    float su = 0.0f;
    for (int i = 0; i < c; i++) su += lu[ip[i]];
    float Ukse = su * invd[e] - 0.5f;
    out[256 + m] = 1.0f / (1.0f + __expf(alpha[e] * Ukse + gamma_e[e]));
}

extern "C" void kernel_launch(void* const* d_in, const int* in_sizes, int n_in,
                              void* d_out, int out_size, void* d_ws, size_t ws_size,
                              hipStream_t stream) {
    const float* U          = (const float*)d_in[0];
    const float* W          = (const float*)d_in[1];
    const float* beiTa_1    = (const float*)d_in[2];
    const float* beiTa_2    = (const float*)d_in[3];
    const float* B          = (const float*)d_in[4];
    const float* guess_slip = (const float*)d_in[5];
    const float* A_emb      = (const float*)d_in[6];
    const float* gamma_c    = (const float*)d_in[7];
    const float* gamma_e    = (const float*)d_in[8];
    const float* alpha      = (const float*)d_in[9];
    const float* score      = (const float*)d_in[10];
    const float* ukc        = (const float*)d_in[11];
    const float* q_kn       = (const float*)d_in[12];
    const float* d          = (const float*)d_in[13];
    const int*   stu_id     = (const int*)d_in[14];
    const int*   ex_id      = (const int*)d_in[16];
    float* out = (float*)d_out;
    float* ws  = (float*)d_ws;

    k_setup<<<272, 256, 0, stream>>>(U, W, beiTa_1, beiTa_2, guess_slip, A_emb,
                                     gamma_c, score, ukc, q_kn, d, stu_id, ws);
    k_mega<<<NB, 256, 0, stream>>>(B, ws, out, ex_id, alpha, gamma_e);
}

// Round 5
// 457.047 us; speedup vs baseline: 2.8169x; 2.8169x over previous
//
#include <hip/hip_runtime.h>
#include <math.h>

#define KK 128
#define EE 4096
#define MM 512
#define CP 32   // max nnz per q_kn row (c<=32 verified: absmax exactly 0 in prior rounds)

// ws float-offset layout (~72 MB of the 1 GiB ws):
#define OFF_U    0              // u[128] (current state)
#define OFF_PA   128            // partials A [128][16]
#define OFF_PB   2176           // partials B [128][16]
#define OFF_CNT  4224           // int cnt[E]
#define OFF_IDX  8320           // signed char idx[E][CP]  (row-major, sentinel -1)
#define OFF_IDXT 41088          // signed char idxT[CP][E] (i-major, sentinel -1)
#define OFF_PE   73856          // P01, a2, scv, invd, bz  (5 x E floats)
#define OFF_GW   94336          // gW[k][e] = ukc*W*beiTa_1
#define OFF_HW   618624         // hW[k][e] = ukc*W
#define OFF_BC   1142912        // Bc[k][i][e] compacted B (64 MB)

// NOTE (r2/r3 lesson, recorded): in-kernel grid barriers on MI355X cost
// ~150-350us each here (per-block-leader device-scope fences -> L2
// writeback/invalidate storms across 8 non-coherent XCD L2s). Dispatch
// boundaries do the same sync for ~5-10us. Multi-dispatch is the right
// structure for this op; the only safe fusion is same-block producer->consumer.

// K1: blocks 0..15 per-e lists + constants + u0; blocks 16..271 gW/hW.
__global__ __launch_bounds__(256) void k_setup(
    const float* __restrict__ U, const float* __restrict__ W,
    const float* __restrict__ beiTa_1, const float* __restrict__ beiTa_2,
    const float* __restrict__ guess_slip, const float* __restrict__ A_emb,
    const float* __restrict__ gamma_c, const float* __restrict__ score,
    const float* __restrict__ ukc, const float* __restrict__ q_kn,
    const float* __restrict__ d, const int* __restrict__ stu_id,
    float* __restrict__ ws)
{
    int tid = threadIdx.x;
    int blk = blockIdx.x;
    if (blk < 16) {
        int e = blk * 256 + tid;
        int* cnt = (int*)(ws + OFF_CNT);
        signed char* idx  = (signed char*)(ws + OFF_IDX);
        signed char* idxT = (signed char*)(ws + OFF_IDXT);
        float* P01  = ws + OFF_PE;
        float* a2   = P01 + EE;
        float* scv  = a2 + EE;
        float* invd = scv + EE;
        float* bz   = invd + EE;

        // sentinel-fill this e's idx row (-1 bytes), then pack ascending support
        int* ip32 = (int*)(idx + e * CP);
        #pragma unroll
        for (int t = 0; t < CP / 4; t++) ip32[t] = -1;
        const float4* qrow = (const float4*)(q_kn + (size_t)e * KK);
        int c = 0;
        for (int j4 = 0; j4 < KK / 4; j4++) {
            float4 q = qrow[j4];
            int j = j4 * 4;
            if (q.x > 0.5f) { if (c < CP) idx[e*CP+c] = (signed char)j;     c++; }
            if (q.y > 0.5f) { if (c < CP) idx[e*CP+c] = (signed char)(j+1); c++; }
            if (q.z > 0.5f) { if (c < CP) idx[e*CP+c] = (signed char)(j+2); c++; }
            if (q.w > 0.5f) { if (c < CP) idx[e*CP+c] = (signed char)(j+3); c++; }
        }
        c = (c < CP) ? c : CP;
        cnt[e] = c;
        // transposed copy (coalesced over e for each i)
        for (int i = 0; i < CP; i++) idxT[(size_t)i * EE + e] = idx[e * CP + i];

        float id_ = 1.0f / d[e];
        invd[e] = id_;
        float scr = score[e];
        scv[e] = scr;
        P01[e] = A_emb[3*e] * (1.0f - guess_slip[2*e]) +
                 A_emb[3*e+1] * (1.0f - guess_slip[2*e+1]);
        a2[e] = A_emb[3*e+2];
        float zc = 1.0f / (1.0f + __expf(gamma_c[e] * id_ * (scr - 0.5f))) - 0.5f;
        bz[e] = beiTa_2[e] * zc;

        if (blk == 0 && tid < KK) ws[tid] = U[(size_t)stu_id[0] * KK + tid];
    } else {
        float* gW = ws + OFF_GW;
        float* hW = ws + OFF_HW;
        int stride = 256 * 256;
        for (int t = (blk - 16) * 256 + tid; t < KK * EE; t += stride) {
            float uw = ukc[t] * W[t];
            hW[t] = uw;
            gW[t] = uw * beiTa_1[t];
        }
    }
}

// K2: fused compaction + phase 0. Block (ec 0..15, k 0..127) compacts exactly
// the 4 B-units (k, e0 = ec*256 + t*64) whose Bc slice it alone reads for its
// phase-0 e-range [ec*256, ec*256+256). Same-block producer->consumer through
// the local XCD L2 -> no grid sync needed (pattern proven correct in r3).
__global__ __launch_bounds__(256) void k_cp0(
    const float* __restrict__ B, float* __restrict__ ws, float* __restrict__ pout)
{
    __shared__ float lds[64 * KK];   // 32 KB staging; reused as lu/sdv/wred after
    int tid = threadIdx.x;
    int ec = blockIdx.x;   // 0..15
    int k  = blockIdx.y;   // 0..127

    const signed char* idxT = (const signed char*)(ws + OFF_IDXT);
    float* Bc = ws + OFF_BC;

    // ---- compact my 4 units ----
    for (int t4 = 0; t4 < 4; t4++) {
        int e0 = ec * 256 + t4 * 64;
        const float4* src = (const float4*)(B + ((size_t)k * EE + e0) * KK);
        float4* dst4 = (float4*)lds;
        #pragma unroll
        for (int it = 0; it < 8; it++)
            dst4[it * 256 + tid] = src[it * 256 + tid];
        __syncthreads();
        int eo = tid & 63;
        float* BcB = Bc + (size_t)k * CP * EE + e0 + eo;
        for (int i = tid >> 6; i < CP; i += 4) {
            int j = idxT[(size_t)i * EE + e0 + eo];
            unsigned long long m = __ballot(j >= 0);
            if (!m) break;
            if (j >= 0) BcB[(size_t)i * EE] = lds[eo * KK + j];
        }
        __syncthreads();
    }

    // ---- phase 0 (identical arithmetic to k_phase p==0) ----
    float* lu   = lds;         // [128]
    float* sdv  = lds + 128;   // [128]
    float* wred = lds + 256;   // [4]
    if (tid < KK) {
        float uv = ws[tid];
        lu[tid] = uv;
        float t = uv - 0.5f;
        sdv[tid] = (fabsf(t) > 0.05f) ? t : 0.0f;
    }
    __syncthreads();

    const int* cnt = (const int*)(ws + OFF_CNT);
    const float* P01  = ws + OFF_PE;
    const float* a2   = P01 + EE;
    const float* scv  = a2 + EE;
    const float* invd = scv + EE;
    const float* bzv  = invd + EE;
    const float* gW   = ws + OFF_GW;
    const float* hW   = ws + OFF_HW;

    int e = ec * 256 + tid;
    int c = cnt[e];
    const signed char* it = idxT + e;
    const float* bp = Bc + (size_t)k * CP * EE + e;
    float su = 0.0f, gs = 0.0f;
    for (int i = 0; i < c; i++) {
        int j   = it[(size_t)i * EE];
        float b = bp[(size_t)i * EE];
        su += lu[j];
        gs = fmaf(b, (j != k) ? sdv[j] : 0.0f, gs);   // diag term cancels exactly
    }
    float t0 = scv[e] - su * invd[e];
    float yc = __expf(-t0 * t0);
    float Ic = 1.0f / (1.0f + __expf(P01[e] + a2[e] * yc));
    float Gkc = 1.0f / (1.0f + __expf(gs)) - 1.0f;
    size_t o = (size_t)k * EE + e;
    float v = Ic * (gW[o] * Gkc + hW[o] * bzv[e]);

    #pragma unroll
    for (int m = 1; m < 64; m <<= 1) v += __shfl_xor(v, m);
    if ((tid & 63) == 0) wred[tid >> 6] = v;
    __syncthreads();
    if (tid == 0) pout[k * 16 + ec] = wred[0] + wred[1] + wred[2] + wred[3];
}

// K3: one model iteration (phase 1/2). Block = (e-chunk 256, k).
// Every block re-reduces pin -> u locally; block(0,0) does diff bookkeeping.
__global__ __launch_bounds__(256) void k_phase(
    float* __restrict__ ws, float* __restrict__ out,
    const float* __restrict__ pin, float* __restrict__ pout, int phase)
{
    __shared__ float lu[KK];
    __shared__ float sdv[KK];
    __shared__ float red2[KK];
    __shared__ float wred[4];
    int tid = threadIdx.x;
    int ec = blockIdx.x;   // 0..15
    int k  = blockIdx.y;   // 0..127
    int e  = ec * 256 + tid;

    if (tid < KK) {
        float s = 0.0f;
        const float* p = pin + tid * 16;
        #pragma unroll
        for (int t = 0; t < 16; t++) s += p[t];
        float uv = 1.0f / (1.0f + __expf(s));
        lu[tid] = uv;
        float t = uv - 0.5f;
        sdv[tid] = (fabsf(t) > 0.05f) ? t : 0.0f;
    }
    __syncthreads();

    const int* cnt = (const int*)(ws + OFF_CNT);
    const signed char* idxT = (const signed char*)(ws + OFF_IDXT);
    const float* P01  = ws + OFF_PE;
    const float* a2   = P01 + EE;
    const float* scv  = a2 + EE;
    const float* invd = scv + EE;
    const float* bzv  = invd + EE;
    const float* gW   = ws + OFF_GW;
    const float* hW   = ws + OFF_HW;
    const float* Bc   = ws + OFF_BC;

    int c = cnt[e];
    const signed char* it = idxT + e;
    const float* bp = Bc + (size_t)k * CP * EE + e;
    float su = 0.0f, gs = 0.0f;
    for (int i = 0; i < c; i++) {
        int j   = it[(size_t)i * EE];
        float b = bp[(size_t)i * EE];
        su += lu[j];
        gs = fmaf(b, (j != k) ? sdv[j] : 0.0f, gs);   // diag term cancels exactly
    }
    float t0 = scv[e] - su * invd[e];
    float yc = __expf(-t0 * t0);
    float Ic = 1.0f / (1.0f + __expf(P01[e] + a2[e] * yc));
    float Gkc = 1.0f / (1.0f + __expf(gs)) - 1.0f;
    size_t o = (size_t)k * EE + e;
    float v = Ic * (gW[o] * Gkc + hW[o] * bzv[e]);

    #pragma unroll
    for (int m = 1; m < 64; m <<= 1) v += __shfl_xor(v, m);
    if ((tid & 63) == 0) wred[tid >> 6] = v;
    __syncthreads();
    if (tid == 0) pout[k * 16 + ec] = wred[0] + wred[1] + wred[2] + wred[3];

    // bookkeeping: diff norm of previous update, advance ws-u, state_2nd_last
    if (blockIdx.x == 0 && blockIdx.y == 0) {
        if (tid < KK) {
            float dd = lu[tid] - ws[tid];
            red2[tid] = dd * dd;
        }
        __syncthreads();
        for (int s2 = 64; s2 > 0; s2 >>= 1) {
            if (tid < s2) red2[tid] += red2[tid + s2];
            __syncthreads();
        }
        if (tid == 0) out[768 + (phase - 1)] = sqrtf(red2[0]);
        if (tid < KK) {
            ws[tid] = lu[tid];
            if (phase == 2) out[128 + tid] = lu[tid];   // state_2nd_last
        }
    }
}

// K4: final update + diff + state_last + predict (M=512)
__global__ __launch_bounds__(512) void k_final(
    float* __restrict__ ws, float* __restrict__ out, const float* __restrict__ pin,
    const int* __restrict__ ex_id, const float* __restrict__ alpha,
    const float* __restrict__ gamma_e)
{
    __shared__ float un_s[KK];
    __shared__ float red[KK];
    int tid = threadIdx.x;
    if (tid < KK) {
        float s = 0.0f;
        const float* p = pin + tid * 16;
        #pragma unroll
        for (int t = 0; t < 16; t++) s += p[t];
        float un = 1.0f / (1.0f + __expf(s));
        float dd = un - ws[tid];
        red[tid] = dd * dd;
        un_s[tid] = un;
        out[tid] = un;   // state_last
    }
    __syncthreads();
    for (int s2 = 64; s2 > 0; s2 >>= 1) {
        if (tid < s2) red[tid] += red[tid + s2];
        __syncthreads();
    }
    if (tid == 0) out[770] = sqrtf(red[0]);

    const int* cnt = (const int*)(ws + OFF_CNT);
    const signed char* idx = (const signed char*)(ws + OFF_IDX);
    const float* invd = ws + OFF_PE + 3 * EE;
    int e = ex_id[tid];
    int c = cnt[e];
    const signed char* ip = idx + (size_t)e * CP;
    float su = 0.0f;
    for (int i = 0; i < c; i++) su += un_s[ip[i]];
    float Ukse = su * invd[e] - 0.5f;
    out[256 + tid] = 1.0f / (1.0f + __expf(alpha[e] * Ukse + gamma_e[e]));
}

extern "C" void kernel_launch(void* const* d_in, const int* in_sizes, int n_in,
                              void* d_out, int out_size, void* d_ws, size_t ws_size,
                              hipStream_t stream) {
    const float* U          = (const float*)d_in[0];
    const float* W          = (const float*)d_in[1];
    const float* beiTa_1    = (const float*)d_in[2];
    const float* beiTa_2    = (const float*)d_in[3];
    const float* B          = (const float*)d_in[4];
    const float* guess_slip = (const float*)d_in[5];
    const float* A_emb      = (const float*)d_in[6];
    const float* gamma_c    = (const float*)d_in[7];
    const float* gamma_e    = (const float*)d_in[8];
    const float* alpha      = (const float*)d_in[9];
    const float* score      = (const float*)d_in[10];
    const float* ukc        = (const float*)d_in[11];
    const float* q_kn       = (const float*)d_in[12];
    const float* d          = (const float*)d_in[13];
    const int*   stu_id     = (const int*)d_in[14];
    const int*   ex_id      = (const int*)d_in[16];
    float* out = (float*)d_out;
    float* ws  = (float*)d_ws;
    float* pA = ws + OFF_PA;
    float* pB = ws + OFF_PB;

    k_setup<<<272, 256, 0, stream>>>(U, W, beiTa_1, beiTa_2, guess_slip, A_emb,
                                     gamma_c, score, ukc, q_kn, d, stu_id, ws);
    k_cp0<<<dim3(16, 128), 256, 0, stream>>>(B, ws, pA);
    k_phase<<<dim3(16, 128), 256, 0, stream>>>(ws, out, pA, pB, 1);
    k_phase<<<dim3(16, 128), 256, 0, stream>>>(ws, out, pB, pA, 2);
    k_final<<<1, 512, 0, stream>>>(ws, out, pA, ex_id, alpha, gamma_e);
}